// Round 3
// baseline (221.346 us; speedup 1.0000x reference)
//
#include <hip/hip_runtime.h>
#include <hip/hip_bf16.h>

typedef unsigned short u16;
typedef short s16x8 __attribute__((ext_vector_type(8)));
typedef float f32x4 __attribute__((ext_vector_type(4)));

// fp32 -> bf16 round-to-nearest-even
__device__ inline u16 f2bf(float f) {
  union { float f; unsigned int u; } v; v.f = f;
  unsigned int r = v.u + 0x7fffu + ((v.u >> 16) & 1u);
  return (u16)(r >> 16);
}

// async 16B global -> LDS DMA (lane i of the wave lands at ldsbase + i*16)
__device__ __forceinline__ void g2lds16(const u16* g, u16* l) {
  __builtin_amdgcn_global_load_lds((const __attribute__((address_space(1))) void*)g,
                                   (__attribute__((address_space(3))) void*)l, 16, 0, 0);
}

// ---------------------------------------------------------------- cast x -> bf16
__global__ __launch_bounds__(256) void cast_x_kernel(const float* __restrict__ x,
                                                     u16* __restrict__ xb) {
  int i = (blockIdx.x * 256 + threadIdx.x) * 8;
  float4 a = *(const float4*)(x + i);
  float4 b = *(const float4*)(x + i + 4);
  s16x8 o;
  o[0] = (short)f2bf(a.x); o[1] = (short)f2bf(a.y);
  o[2] = (short)f2bf(a.z); o[3] = (short)f2bf(a.w);
  o[4] = (short)f2bf(b.x); o[5] = (short)f2bf(b.y);
  o[6] = (short)f2bf(b.z); o[7] = (short)f2bf(b.w);
  *(s16x8*)(xb + i) = o;
}

// ---------------------------------------------------------------- W -> Wt bf16, all three in one launch
// z=0: Wq (512x1024, rowoff 0), z=1: Wk (512x1024, rowoff 1024), z=2: Wv (512x512, rowoff 2048)
__global__ __launch_bounds__(256) void transpose_cast_w3(const float* __restrict__ Wq,
                                                         const float* __restrict__ Wk,
                                                         const float* __restrict__ Wv,
                                                         u16* __restrict__ wt) {
  int z = blockIdx.z;
  if (z == 2 && blockIdx.x >= 8) return;       // Wv has only 8 j-tiles
  const float* src = (z == 0) ? Wq : (z == 1) ? Wk : Wv;
  int C = (z == 2) ? 512 : 1024;
  int rowoff = z * 1024;
  __shared__ float tile[64][65];
  int j0 = blockIdx.x * 64, k0 = blockIdx.y * 64;
  int tx = threadIdx.x % 64, ty4 = threadIdx.x / 64;
#pragma unroll
  for (int p = 0; p < 16; ++p) {
    int r = p * 4 + ty4;
    tile[r][tx] = src[(size_t)(k0 + r) * C + j0 + tx];
  }
  __syncthreads();
#pragma unroll
  for (int p = 0; p < 16; ++p) {
    int r = p * 4 + ty4;
    wt[(size_t)(rowoff + j0 + r) * 512 + k0 + tx] = f2bf(tile[tx][r]);
  }
}

// ---------------------------------------------------------------- fused QKV projection GEMM
// m97 recipe + DMA double-buffer: prefetch for k-tile t+1 is issued AFTER the barrier that
// drains tile t, so it stays in flight across the whole compute of tile t (one barrier/iter).
__global__ __launch_bounds__(256, 2) void gemm_qkv(const u16* __restrict__ xb, const u16* __restrict__ wt,
                                                   const float* __restrict__ bq, const float* __restrict__ bk,
                                                   const float* __restrict__ bv,
                                                   u16* __restrict__ qa, u16* __restrict__ ka,
                                                   u16* __restrict__ va) {
  __shared__ __align__(16) u16 As[2][128 * 64];
  __shared__ __align__(16) u16 Bs[2][128 * 64];
  int m0 = blockIdx.x * 128, j0 = blockIdx.y * 128;
  int tid = threadIdx.x;
  int w = tid >> 6, lane = tid & 63, quad = lane >> 4, l16 = lane & 15;
  int wr = (w >> 1) * 64, wc = (w & 1) * 64;

  // staging: slot s = it*256+tid; row = s>>3, logical chunk = (s&7)^(row&7), lds base wave-uniform
  int srow[4], scol[4], sbase[4];
#pragma unroll
  for (int it = 0; it < 4; ++it) {
    int s = it * 256 + tid;
    srow[it] = s >> 3;
    scol[it] = (s & 7) ^ ((s >> 3) & 7);
    sbase[it] = (s & ~63) * 8;
  }

  f32x4 acc[4][4];
#pragma unroll
  for (int i = 0; i < 4; ++i)
#pragma unroll
    for (int j = 0; j < 4; ++j)
#pragma unroll
      for (int r = 0; r < 4; ++r) acc[i][j][r] = 0.f;

  auto stage = [&](int kk, int bi) {
    int k0 = kk * 64;
#pragma unroll
    for (int it = 0; it < 4; ++it) {
      g2lds16(xb + (size_t)(m0 + srow[it]) * 512 + k0 + scol[it] * 8, &As[bi][sbase[it]]);
      g2lds16(wt + (size_t)(j0 + srow[it]) * 512 + k0 + scol[it] * 8, &Bs[bi][sbase[it]]);
    }
  };

  stage(0, 0);
  for (int kk = 0; kk < 8; ++kk) {
    __syncthreads();                   // drains DMA for buf kk&1; alt-buf reads finished last iter
    if (kk < 7) stage(kk + 1, (kk + 1) & 1);   // in flight during compute below
    int bi = kk & 1;
#pragma unroll
    for (int kb = 0; kb < 2; ++kb) {
      s16x8 af[4], bfr[4];
#pragma unroll
      for (int rb = 0; rb < 4; ++rb) {
        int row = wr + rb * 16 + l16;
        af[rb] = *(const s16x8*)(&As[bi][row * 64 + (((kb * 4 + quad) ^ (row & 7)) * 8)]);
      }
#pragma unroll
      for (int cb = 0; cb < 4; ++cb) {
        int row = wc + cb * 16 + l16;
        bfr[cb] = *(const s16x8*)(&Bs[bi][row * 64 + (((kb * 4 + quad) ^ (row & 7)) * 8)]);
      }
#pragma unroll
      for (int rb = 0; rb < 4; ++rb)
#pragma unroll
        for (int cb = 0; cb < 4; ++cb)
          acc[rb][cb] = __builtin_amdgcn_mfma_f32_16x16x32_bf16(af[rb], bfr[cb], acc[rb][cb], 0, 0, 0);
    }
  }

#pragma unroll
  for (int cb = 0; cb < 4; ++cb) {
    int j = j0 + wc + cb * 16 + l16;
    float bias = (j < 1024) ? bq[j] : (j < 2048) ? bk[j - 1024] : bv[j - 2048];
#pragma unroll
    for (int rb = 0; rb < 4; ++rb) {
#pragma unroll
      for (int r = 0; r < 4; ++r) {
        int m = m0 + wr + rb * 16 + quad * 4 + r;
        int bidx = m >> 10, n = m & 1023;
        u16 o = f2bf(acc[rb][cb][r] + bias);
        if (j < 1024) {
          int h = j >> 7, r2 = j & 127;
          qa[((size_t)((bidx * 8 + h) * 1024 + n)) * 128 + r2] = o;
        } else if (j < 2048) {
          int jj = j - 1024, h = jj >> 7, r2 = jj & 127;
          ka[((size_t)((bidx * 8 + h) * 1024 + n)) * 128 + r2] = o;
        } else {                              // v transposed: [b][h][d][n]
          int jj = j - 2048, h = jj >> 6, d = jj & 63;
          va[((size_t)((bidx * 8 + h) * 64 + d)) * 1024 + n] = o;
        }
      }
    }
  }
}

// ---------------------------------------------------------------- differential attention v3
// In-WG split-K: 1024 WGs (bh, 32-row Q-tile). Wave w: q-rows q0+(w&1)*16, key-half kh=w>>1.
// K-step 32, reg-prefetch staging (34 KB LDS -> up to 4 WG/CU = 16 waves/CU).
// Partial (O, l) of the two key-halves combined through LDS in the epilogue (fp32, no HBM spill).
__global__ __launch_bounds__(256, 3) void attn_kernel(const u16* __restrict__ qa, const u16* __restrict__ ka,
                                                      const u16* __restrict__ va, float* __restrict__ out) {
  __shared__ __align__(16) u16 smem[17408];   // 34816 B
  u16* Ks = smem;                 // [kh][32 keys][128 feat], 16B-chunk swizzle ^(row&7)  (16 KB)
  u16* Vs = smem + 8192;          // [kh][64 d][32 n], chunk swizzle ^(row&3)             (8 KB)
  u16* Ps = smem + 12288;         // [wave][hh][16 rows][40 cols]                        (10 KB)
  float* Ex = (float*)smem;       // epilogue overlay: [wi][hh][16][68] f32 = 17408 B over Ks+Vs

  int bh = blockIdx.x, b = bh >> 3, h = bh & 7;
  int q0 = blockIdx.y * 32;
  int tid = threadIdx.x, w = tid >> 6, lane = tid & 63, quad = lane >> 4, l16 = lane & 15;
  int kh = w >> 1;
  int qr = q0 + (w & 1) * 16;

  const u16* kgbase = ka + (size_t)bh * 1024 * 128;
  const u16* vgbase = va + (size_t)bh * 64 * 1024;

  // q fragments (persist whole kernel)
  const u16* qrow = qa + (size_t)(bh * 1024 + qr + l16) * 128;
  s16x8 qf[2][2];
  qf[0][0] = *(const s16x8*)(qrow + quad * 8);
  qf[0][1] = *(const s16x8*)(qrow + 32 + quad * 8);
  qf[1][0] = *(const s16x8*)(qrow + 64 + quad * 8);
  qf[1][1] = *(const s16x8*)(qrow + 96 + quad * 8);

  f32x4 O1[5], O2[5];
#pragma unroll
  for (int i = 0; i < 5; ++i)
#pragma unroll
    for (int r = 0; r < 4; ++r) { O1[i][r] = 0.f; O2[i][r] = 0.f; }

  s16x8 onesf;   // B-frag of the ones column: 1.0 only on lanes with l16==0
#pragma unroll
  for (int i = 0; i < 8; ++i) onesf[i] = (l16 == 0) ? (short)0x3F80 : (short)0;

  // staging maps. K: 1024 chunk-slots (4/thread): s -> kh=s>>9, row=(s&511)>>4, c=s&15.
  int kго_dummy = 0; (void)kго_dummy;
  int kldso[4]; size_t kgo[4];
#pragma unroll
  for (int i = 0; i < 4; ++i) {
    int s = i * 256 + tid;
    int skh = s >> 9, r = s & 511, row = r >> 4, c = r & 15;
    kldso[i] = skh * 4096 + row * 128 + ((c ^ (row & 7)) * 8);
    kgo[i] = (size_t)(skh * 512 + row) * 128 + c * 8;          // + kt*32*128
  }
  // V: 512 chunk-slots (2/thread): s -> kh=s>>8, row=(s&255)>>2, c=s&3.
  int vldso[2]; size_t vgo[2];
#pragma unroll
  for (int i = 0; i < 2; ++i) {
    int s = i * 256 + tid;
    int skh = s >> 8, r = s & 255, row = r >> 2, c = r & 3;
    vldso[i] = skh * 2048 + row * 32 + ((c ^ (row & 3)) * 8);
    vgo[i] = (size_t)row * 1024 + skh * 512 + c * 8;           // + kt*32
  }

  int4 kreg[4], vreg[2];
#pragma unroll
  for (int i = 0; i < 4; ++i) kreg[i] = *(const int4*)(kgbase + kgo[i]);
#pragma unroll
  for (int i = 0; i < 2; ++i) vreg[i] = *(const int4*)(vgbase + vgo[i]);

  for (int kt = 0; kt < 16; ++kt) {
    // write staged regs -> LDS (region free per previous loop-end barrier)
#pragma unroll
    for (int i = 0; i < 4; ++i) *(int4*)(&Ks[kldso[i]]) = kreg[i];
#pragma unroll
    for (int i = 0; i < 2; ++i) *(int4*)(&Vs[vldso[i]]) = vreg[i];
    __syncthreads();                                   // writes visible to all waves
    int ktn = (kt < 15) ? kt + 1 : 15;                 // last prefetch is a discarded re-read
#pragma unroll
    for (int i = 0; i < 4; ++i) kreg[i] = *(const int4*)(kgbase + kgo[i] + (size_t)ktn * 4096);
#pragma unroll
    for (int i = 0; i < 2; ++i) vreg[i] = *(const int4*)(vgbase + vgo[i] + (size_t)ktn * 32);

    // V fragments: B[k=key][n=d]; lane l16 = d-col, k = quad*8+j
    s16x8 vf[4];
#pragma unroll
    for (int ct = 0; ct < 4; ++ct) {
      int row = ct * 16 + l16;
      vf[ct] = *(const s16x8*)(&Vs[kh * 2048 + row * 32 + ((quad ^ (row & 3)) * 8)]);
    }

    // QK^T both halves -> exp -> Ps (wave-private rows)
#pragma unroll
    for (int hh = 0; hh < 2; ++hh) {
#pragma unroll
      for (int nt = 0; nt < 2; ++nt) {
        f32x4 sv; sv[0] = sv[1] = sv[2] = sv[3] = 0.f;
#pragma unroll
        for (int kb = 0; kb < 2; ++kb) {
          int row = nt * 16 + l16;
          s16x8 kf = *(const s16x8*)(&Ks[kh * 4096 + row * 128 +
                                         (((hh * 8 + kb * 4 + quad) ^ (row & 7)) * 8)]);
          sv = __builtin_amdgcn_mfma_f32_16x16x32_bf16(qf[hh][kb], kf, sv, 0, 0, 0);
        }
#pragma unroll
        for (int r = 0; r < 4; ++r)
          Ps[((w * 2 + hh) * 16 + quad * 4 + r) * 40 + nt * 16 + l16] = f2bf(__expf(sv[r] * 0.125f));
      }
    }
    asm volatile("s_waitcnt lgkmcnt(0)" ::: "memory");  // P writes retired before re-read
    s16x8 pf0 = *(const s16x8*)(&Ps[((w * 2 + 0) * 16 + l16) * 40 + quad * 8]);
    s16x8 pf1 = *(const s16x8*)(&Ps[((w * 2 + 1) * 16 + l16) * 40 + quad * 8]);
#pragma unroll
    for (int ct = 0; ct < 5; ++ct) {
      s16x8 bfr = (ct < 4) ? vf[ct] : onesf;
      O1[ct] = __builtin_amdgcn_mfma_f32_16x16x32_bf16(pf0, bfr, O1[ct], 0, 0, 0);
      O2[ct] = __builtin_amdgcn_mfma_f32_16x16x32_bf16(pf1, bfr, O2[ct], 0, 0, 0);
    }
    __syncthreads();   // all waves done reading tile kt -> LDS writable next iter
  }

  // ---- combine key-halves through LDS (waves 2,3 -> waves 0,1) ----
  if (w >= 2) {
    int wi = w - 2;
#pragma unroll
    for (int ct = 0; ct < 4; ++ct)
#pragma unroll
      for (int r = 0; r < 4; ++r) {
        Ex[((wi * 2 + 0) * 16 + quad * 4 + r) * 68 + ct * 16 + l16] = O1[ct][r];
        Ex[((wi * 2 + 1) * 16 + quad * 4 + r) * 68 + ct * 16 + l16] = O2[ct][r];
      }
    if (l16 == 0) {
#pragma unroll
      for (int r = 0; r < 4; ++r) {
        Ex[((wi * 2 + 0) * 16 + quad * 4 + r) * 68 + 64] = O1[4][r];
        Ex[((wi * 2 + 1) * 16 + quad * 4 + r) * 68 + 64] = O2[4][r];
      }
    }
  }
  __syncthreads();
  if (w < 2) {
#pragma unroll
    for (int ct = 0; ct < 4; ++ct)
#pragma unroll
      for (int r = 0; r < 4; ++r) {
        O1[ct][r] += Ex[((w * 2 + 0) * 16 + quad * 4 + r) * 68 + ct * 16 + l16];
        O2[ct][r] += Ex[((w * 2 + 1) * 16 + quad * 4 + r) * 68 + ct * 16 + l16];
      }
    if (l16 == 0) {
#pragma unroll
      for (int r = 0; r < 4; ++r) {
        O1[4][r] += Ex[((w * 2 + 0) * 16 + quad * 4 + r) * 68 + 64];
        O2[4][r] += Ex[((w * 2 + 1) * 16 + quad * 4 + r) * 68 + 64];
      }
    }
    float inv1[4], inv2[4];
#pragma unroll
    for (int r = 0; r < 4; ++r) {
      float l1 = __shfl(O1[4][r], lane & 48, 64);
      float l2 = __shfl(O2[4][r], lane & 48, 64);
      inv1[r] = 1.0f / l1;
      inv2[r] = 1.0f / l2;
    }
    int nb = qr + quad * 4;
#pragma unroll
    for (int ct = 0; ct < 4; ++ct)
#pragma unroll
      for (int r = 0; r < 4; ++r) {
        float val = O1[ct][r] * inv1[r] - 0.5f * O2[ct][r] * inv2[r];
        out[(size_t)(b * 1024 + nb + r) * 512 + h * 64 + ct * 16 + l16] = val;
      }
  }
}

// ---------------------------------------------------------------- launcher
extern "C" void kernel_launch(void* const* d_in, const int* in_sizes, int n_in,
                              void* d_out, int out_size, void* d_ws, size_t ws_size,
                              hipStream_t stream) {
  (void)in_sizes; (void)n_in; (void)out_size; (void)ws_size;
  const float* x  = (const float*)d_in[0];
  const float* Wq = (const float*)d_in[1];
  const float* bq = (const float*)d_in[2];
  const float* Wk = (const float*)d_in[3];
  const float* bk = (const float*)d_in[4];
  const float* Wv = (const float*)d_in[5];
  const float* bv = (const float*)d_in[6];
  float* out = (float*)d_out;

  char* ws = (char*)d_ws;
  u16* xb = (u16*)(ws);                    // 4096*512*2   = 4 MiB
  u16* wt = (u16*)(ws + 4194304);          // 2560*512*2   = 2.5 MiB
  u16* qa = (u16*)(ws + 6815744);          // 4*8*1024*128*2 = 8 MiB
  u16* ka = (u16*)(ws + 15204352);         // 8 MiB
  u16* va = (u16*)(ws + 23592960);         // 4*8*64*1024*2 = 4 MiB

  cast_x_kernel<<<1024, 256, 0, stream>>>(x, xb);
  transpose_cast_w3<<<dim3(16, 8, 3), 256, 0, stream>>>(Wq, Wk, Wv, wt);
  gemm_qkv<<<dim3(32, 20), 256, 0, stream>>>(xb, wt, bq, bk, bv, qa, ka, va);
  attn_kernel<<<dim3(32, 32), 256, 0, stream>>>(qa, ka, va, out);
}

// Round 4
// 143.999 us; speedup vs baseline: 1.5371x; 1.5371x over previous
//
#include <hip/hip_runtime.h>
#include <hip/hip_bf16.h>

typedef unsigned short u16;
typedef short s16x8 __attribute__((ext_vector_type(8)));
typedef float f32x4 __attribute__((ext_vector_type(4)));

// fp32 -> bf16 round-to-nearest-even
__device__ inline u16 f2bf(float f) {
  union { float f; unsigned int u; } v; v.f = f;
  unsigned int r = v.u + 0x7fffu + ((v.u >> 16) & 1u);
  return (u16)(r >> 16);
}

// async 16B global -> LDS DMA (lane i of the wave lands at ldsbase + i*16)
__device__ __forceinline__ void g2lds16(const u16* g, u16* l) {
  __builtin_amdgcn_global_load_lds((const __attribute__((address_space(1))) void*)g,
                                   (__attribute__((address_space(3))) void*)l, 16, 0, 0);
}

// ---------------------------------------------------------------- cast x -> bf16
__global__ __launch_bounds__(256) void cast_x_kernel(const float* __restrict__ x,
                                                     u16* __restrict__ xb) {
  int i = (blockIdx.x * 256 + threadIdx.x) * 8;
  float4 a = *(const float4*)(x + i);
  float4 b = *(const float4*)(x + i + 4);
  s16x8 o;
  o[0] = (short)f2bf(a.x); o[1] = (short)f2bf(a.y);
  o[2] = (short)f2bf(a.z); o[3] = (short)f2bf(a.w);
  o[4] = (short)f2bf(b.x); o[5] = (short)f2bf(b.y);
  o[6] = (short)f2bf(b.z); o[7] = (short)f2bf(b.w);
  *(s16x8*)(xb + i) = o;
}

// ---------------------------------------------------------------- W -> Wt bf16, all three in one launch
__global__ __launch_bounds__(256) void transpose_cast_w3(const float* __restrict__ Wq,
                                                         const float* __restrict__ Wk,
                                                         const float* __restrict__ Wv,
                                                         u16* __restrict__ wt) {
  int z = blockIdx.z;
  if (z == 2 && blockIdx.x >= 8) return;       // Wv has only 8 j-tiles
  const float* src = (z == 0) ? Wq : (z == 1) ? Wk : Wv;
  int C = (z == 2) ? 512 : 1024;
  int rowoff = z * 1024;
  __shared__ float tile[64][65];
  int j0 = blockIdx.x * 64, k0 = blockIdx.y * 64;
  int tx = threadIdx.x % 64, ty4 = threadIdx.x / 64;
#pragma unroll
  for (int p = 0; p < 16; ++p) {
    int r = p * 4 + ty4;
    tile[r][tx] = src[(size_t)(k0 + r) * C + j0 + tx];
  }
  __syncthreads();
#pragma unroll
  for (int p = 0; p < 16; ++p) {
    int r = p * 4 + ty4;
    wt[(size_t)(rowoff + j0 + r) * 512 + k0 + tx] = f2bf(tile[tx][r]);
  }
}

// ---------------------------------------------------------------- fused QKV projection GEMM (unchanged: neutral-or-better in R3)
__global__ __launch_bounds__(256, 2) void gemm_qkv(const u16* __restrict__ xb, const u16* __restrict__ wt,
                                                   const float* __restrict__ bq, const float* __restrict__ bk,
                                                   const float* __restrict__ bv,
                                                   u16* __restrict__ qa, u16* __restrict__ ka,
                                                   u16* __restrict__ va) {
  __shared__ __align__(16) u16 As[2][128 * 64];
  __shared__ __align__(16) u16 Bs[2][128 * 64];
  int m0 = blockIdx.x * 128, j0 = blockIdx.y * 128;
  int tid = threadIdx.x;
  int w = tid >> 6, lane = tid & 63, quad = lane >> 4, l16 = lane & 15;
  int wr = (w >> 1) * 64, wc = (w & 1) * 64;

  int srow[4], scol[4], sbase[4];
#pragma unroll
  for (int it = 0; it < 4; ++it) {
    int s = it * 256 + tid;
    srow[it] = s >> 3;
    scol[it] = (s & 7) ^ ((s >> 3) & 7);
    sbase[it] = (s & ~63) * 8;
  }

  f32x4 acc[4][4];
#pragma unroll
  for (int i = 0; i < 4; ++i)
#pragma unroll
    for (int j = 0; j < 4; ++j)
#pragma unroll
      for (int r = 0; r < 4; ++r) acc[i][j][r] = 0.f;

  auto stage = [&](int kk, int bi) {
    int k0 = kk * 64;
#pragma unroll
    for (int it = 0; it < 4; ++it) {
      g2lds16(xb + (size_t)(m0 + srow[it]) * 512 + k0 + scol[it] * 8, &As[bi][sbase[it]]);
      g2lds16(wt + (size_t)(j0 + srow[it]) * 512 + k0 + scol[it] * 8, &Bs[bi][sbase[it]]);
    }
  };

  stage(0, 0);
  for (int kk = 0; kk < 8; ++kk) {
    __syncthreads();
    if (kk < 7) stage(kk + 1, (kk + 1) & 1);
    int bi = kk & 1;
#pragma unroll
    for (int kb = 0; kb < 2; ++kb) {
      s16x8 af[4], bfr[4];
#pragma unroll
      for (int rb = 0; rb < 4; ++rb) {
        int row = wr + rb * 16 + l16;
        af[rb] = *(const s16x8*)(&As[bi][row * 64 + (((kb * 4 + quad) ^ (row & 7)) * 8)]);
      }
#pragma unroll
      for (int cb = 0; cb < 4; ++cb) {
        int row = wc + cb * 16 + l16;
        bfr[cb] = *(const s16x8*)(&Bs[bi][row * 64 + (((kb * 4 + quad) ^ (row & 7)) * 8)]);
      }
#pragma unroll
      for (int rb = 0; rb < 4; ++rb)
#pragma unroll
        for (int cb = 0; cb < 4; ++cb)
          acc[rb][cb] = __builtin_amdgcn_mfma_f32_16x16x32_bf16(af[rb], bfr[cb], acc[rb][cb], 0, 0, 0);
    }
  }

#pragma unroll
  for (int cb = 0; cb < 4; ++cb) {
    int j = j0 + wc + cb * 16 + l16;
    float bias = (j < 1024) ? bq[j] : (j < 2048) ? bk[j - 1024] : bv[j - 2048];
#pragma unroll
    for (int rb = 0; rb < 4; ++rb) {
#pragma unroll
      for (int r = 0; r < 4; ++r) {
        int m = m0 + wr + rb * 16 + quad * 4 + r;
        int bidx = m >> 10, n = m & 1023;
        u16 o = f2bf(acc[rb][cb][r] + bias);
        if (j < 1024) {
          int h = j >> 7, r2 = j & 127;
          qa[((size_t)((bidx * 8 + h) * 1024 + n)) * 128 + r2] = o;
        } else if (j < 2048) {
          int jj = j - 1024, h = jj >> 7, r2 = jj & 127;
          ka[((size_t)((bidx * 8 + h) * 1024 + n)) * 128 + r2] = o;
        } else {                              // v transposed: [b][h][d][n]
          int jj = j - 2048, h = jj >> 6, d = jj & 63;
          va[((size_t)((bidx * 8 + h) * 64 + d)) * 1024 + n] = o;
        }
      }
    }
  }
}

// ---------------------------------------------------------------- differential attention v4
// v3's in-WG split-K grid (1024 WGs: 32-row Q-tile; wave pair per key-half) but staging via
// global_load_lds DMA (zero staging VGPRs -> no scratch spill, the R3 killer) and (256,2).
// Single-buffered LDS (34 KB -> 4 WG/CU = 16 waves/CU); DMA drain hidden by co-resident waves.
__global__ __launch_bounds__(256, 2) void attn_kernel(const u16* __restrict__ qa, const u16* __restrict__ ka,
                                                      const u16* __restrict__ va, float* __restrict__ out) {
  __shared__ __align__(16) u16 smem[17408];   // 34816 B
  u16* Ks = smem;                 // [kh][32 keys][16 chunks], chunk content swizzled ^(row&7)  (16 KB)
  u16* Vs = smem + 8192;          // [kh][64 d][4 chunks], content swizzled ^(row&3)            (8 KB)
  u16* Ps = smem + 12288;         // [wave][hh][16 rows][40 cols]                               (10 KB)
  float* Ex = (float*)smem;       // epilogue overlay: [wi][hh][16][68] f32 = 17408 B over Ks+Vs

  int bh = blockIdx.x, b = bh >> 3, h = bh & 7;
  int q0 = blockIdx.y * 32;
  int tid = threadIdx.x, w = tid >> 6, lane = tid & 63, quad = lane >> 4, l16 = lane & 15;
  int kh = w >> 1;                // key-half this wave reduces over
  int qr = q0 + (w & 1) * 16;

  const u16* kgbase = ka + (size_t)bh * 1024 * 128;
  const u16* vgbase = va + (size_t)bh * 64 * 1024;

  // q fragments (persist whole kernel)
  const u16* qrow = qa + (size_t)(bh * 1024 + qr + l16) * 128;
  s16x8 qf[2][2];
  qf[0][0] = *(const s16x8*)(qrow + quad * 8);
  qf[0][1] = *(const s16x8*)(qrow + 32 + quad * 8);
  qf[1][0] = *(const s16x8*)(qrow + 64 + quad * 8);
  qf[1][1] = *(const s16x8*)(qrow + 96 + quad * 8);

  f32x4 O1[5], O2[5];
#pragma unroll
  for (int i = 0; i < 5; ++i)
#pragma unroll
    for (int r = 0; r < 4; ++r) { O1[i][r] = 0.f; O2[i][r] = 0.f; }

  s16x8 onesf;   // B-frag of the ones column: 1.0 only on lanes with l16==0
#pragma unroll
  for (int i = 0; i < 8; ++i) onesf[i] = (l16 == 0) ? (short)0x3F80 : (short)0;

  // DMA slot maps. Slot s lands at LDS chunk s (wave-uniform base + lane*16).
  // K: 1024 slots: kh=s>>9, row=(s>>4)&31, phys chunk=s&15, logical=phys^(row&7).
  size_t kgo[4]; int kbse[4];
#pragma unroll
  for (int i = 0; i < 4; ++i) {
    int s = i * 256 + tid;
    int skh = s >> 9, row = (s >> 4) & 31, c = s & 15;
    kgo[i] = (size_t)(skh * 512 + row) * 128 + ((c ^ (row & 7)) * 8);   // + kt*32*128
    kbse[i] = (s & ~63) * 8;
  }
  // V: 512 slots: kh=s>>8, row=(s>>2)&63, phys chunk=s&3, logical=phys^(row&3).
  size_t vgo[2]; int vbse[2];
#pragma unroll
  for (int i = 0; i < 2; ++i) {
    int s = i * 256 + tid;
    int skh = s >> 8, row = (s >> 2) & 63, c = s & 3;
    vgo[i] = (size_t)row * 1024 + skh * 512 + ((c ^ (row & 3)) * 8);    // + kt*32
    vbse[i] = (s & ~63) * 8;
  }

  for (int kt = 0; kt < 16; ++kt) {
    __syncthreads();                         // previous tile's LDS reads complete
#pragma unroll
    for (int i = 0; i < 4; ++i)
      g2lds16(kgbase + kgo[i] + (size_t)kt * 4096, &Ks[kbse[i]]);
#pragma unroll
    for (int i = 0; i < 2; ++i)
      g2lds16(vgbase + vgo[i] + (size_t)kt * 32, &Vs[vbse[i]]);
    __syncthreads();                         // barrier drain completes DMA

    // V fragments: B[k=key within half][n=d]
    s16x8 vf[4];
#pragma unroll
    for (int ct = 0; ct < 4; ++ct) {
      int row = ct * 16 + l16;
      vf[ct] = *(const s16x8*)(&Vs[kh * 2048 + row * 32 + ((quad ^ (row & 3)) * 8)]);
    }

    // QK^T both halves -> exp -> Ps (wave-private rows, no barrier)
#pragma unroll
    for (int hh = 0; hh < 2; ++hh) {
#pragma unroll
      for (int nt = 0; nt < 2; ++nt) {
        f32x4 sv; sv[0] = sv[1] = sv[2] = sv[3] = 0.f;
#pragma unroll
        for (int kb = 0; kb < 2; ++kb) {
          int row = nt * 16 + l16;
          s16x8 kf = *(const s16x8*)(&Ks[kh * 4096 + row * 128 +
                                         (((hh * 8 + kb * 4 + quad) ^ (row & 7)) * 8)]);
          sv = __builtin_amdgcn_mfma_f32_16x16x32_bf16(qf[hh][kb], kf, sv, 0, 0, 0);
        }
#pragma unroll
        for (int r = 0; r < 4; ++r)
          Ps[((w * 2 + hh) * 16 + quad * 4 + r) * 40 + nt * 16 + l16] = f2bf(__expf(sv[r] * 0.125f));
      }
    }
    asm volatile("s_waitcnt lgkmcnt(0)" ::: "memory");  // P writes retired before re-read
    s16x8 pf0 = *(const s16x8*)(&Ps[((w * 2 + 0) * 16 + l16) * 40 + quad * 8]);
    s16x8 pf1 = *(const s16x8*)(&Ps[((w * 2 + 1) * 16 + l16) * 40 + quad * 8]);
#pragma unroll
    for (int ct = 0; ct < 5; ++ct) {
      s16x8 bfr = (ct < 4) ? vf[ct] : onesf;
      O1[ct] = __builtin_amdgcn_mfma_f32_16x16x32_bf16(pf0, bfr, O1[ct], 0, 0, 0);
      O2[ct] = __builtin_amdgcn_mfma_f32_16x16x32_bf16(pf1, bfr, O2[ct], 0, 0, 0);
    }
  }
  __syncthreads();   // all waves done with Ks/Vs before Ex overlay

  // ---- combine key-halves through LDS (waves 2,3 -> waves 0,1) ----
  if (w >= 2) {
    int wi = w - 2;
#pragma unroll
    for (int ct = 0; ct < 4; ++ct)
#pragma unroll
      for (int r = 0; r < 4; ++r) {
        Ex[((wi * 2 + 0) * 16 + quad * 4 + r) * 68 + ct * 16 + l16] = O1[ct][r];
        Ex[((wi * 2 + 1) * 16 + quad * 4 + r) * 68 + ct * 16 + l16] = O2[ct][r];
      }
    if (l16 == 0) {
#pragma unroll
      for (int r = 0; r < 4; ++r) {
        Ex[((wi * 2 + 0) * 16 + quad * 4 + r) * 68 + 64] = O1[4][r];
        Ex[((wi * 2 + 1) * 16 + quad * 4 + r) * 68 + 64] = O2[4][r];
      }
    }
  }
  __syncthreads();
  if (w < 2) {
#pragma unroll
    for (int ct = 0; ct < 4; ++ct)
#pragma unroll
      for (int r = 0; r < 4; ++r) {
        O1[ct][r] += Ex[((w * 2 + 0) * 16 + quad * 4 + r) * 68 + ct * 16 + l16];
        O2[ct][r] += Ex[((w * 2 + 1) * 16 + quad * 4 + r) * 68 + ct * 16 + l16];
      }
    if (l16 == 0) {
#pragma unroll
      for (int r = 0; r < 4; ++r) {
        O1[4][r] += Ex[((w * 2 + 0) * 16 + quad * 4 + r) * 68 + 64];
        O2[4][r] += Ex[((w * 2 + 1) * 16 + quad * 4 + r) * 68 + 64];
      }
    }
    float inv1[4], inv2[4];
#pragma unroll
    for (int r = 0; r < 4; ++r) {
      float l1 = __shfl(O1[4][r], lane & 48, 64);
      float l2 = __shfl(O2[4][r], lane & 48, 64);
      inv1[r] = 1.0f / l1;
      inv2[r] = 1.0f / l2;
    }
    int nb = qr + quad * 4;
#pragma unroll
    for (int ct = 0; ct < 4; ++ct)
#pragma unroll
      for (int r = 0; r < 4; ++r) {
        float val = O1[ct][r] * inv1[r] - 0.5f * O2[ct][r] * inv2[r];
        out[(size_t)(b * 1024 + nb + r) * 512 + h * 64 + ct * 16 + l16] = val;
      }
  }
}

// ---------------------------------------------------------------- launcher
extern "C" void kernel_launch(void* const* d_in, const int* in_sizes, int n_in,
                              void* d_out, int out_size, void* d_ws, size_t ws_size,
                              hipStream_t stream) {
  (void)in_sizes; (void)n_in; (void)out_size; (void)ws_size;
  const float* x  = (const float*)d_in[0];
  const float* Wq = (const float*)d_in[1];
  const float* bq = (const float*)d_in[2];
  const float* Wk = (const float*)d_in[3];
  const float* bk = (const float*)d_in[4];
  const float* Wv = (const float*)d_in[5];
  const float* bv = (const float*)d_in[6];
  float* out = (float*)d_out;

  char* ws = (char*)d_ws;
  u16* xb = (u16*)(ws);                    // 4096*512*2   = 4 MiB
  u16* wt = (u16*)(ws + 4194304);          // 2560*512*2   = 2.5 MiB
  u16* qa = (u16*)(ws + 6815744);          // 4*8*1024*128*2 = 8 MiB
  u16* ka = (u16*)(ws + 15204352);         // 8 MiB
  u16* va = (u16*)(ws + 23592960);         // 4*8*64*1024*2 = 4 MiB

  cast_x_kernel<<<1024, 256, 0, stream>>>(x, xb);
  transpose_cast_w3<<<dim3(16, 8, 3), 256, 0, stream>>>(Wq, Wk, Wv, wt);
  gemm_qkv<<<dim3(32, 20), 256, 0, stream>>>(xb, wt, bq, bk, bv, qa, ka, va);
  attn_kernel<<<dim3(32, 32), 256, 0, stream>>>(qa, ka, va, out);
}

// Round 5
// 139.963 us; speedup vs baseline: 1.5815x; 1.0288x over previous
//
#include <hip/hip_runtime.h>
#include <hip/hip_bf16.h>

typedef unsigned short u16;
typedef short s16x8 __attribute__((ext_vector_type(8)));
typedef float f32x4 __attribute__((ext_vector_type(4)));

// fp32 -> bf16 round-to-nearest-even
__device__ inline u16 f2bf(float f) {
  union { float f; unsigned int u; } v; v.f = f;
  unsigned int r = v.u + 0x7fffu + ((v.u >> 16) & 1u);
  return (u16)(r >> 16);
}

// async 16B global -> LDS DMA (lane i of the wave lands at ldsbase + i*16)
__device__ __forceinline__ void g2lds16(const u16* g, u16* l) {
  __builtin_amdgcn_global_load_lds((const __attribute__((address_space(1))) void*)g,
                                   (__attribute__((address_space(3))) void*)l, 16, 0, 0);
}

// ---------------------------------------------------------------- prep: cast x + transpose-cast W (one launch)
// blocks [0,1024): cast x -> xb. [1024,1152): Wq. [1152,1280): Wk. [1280,1344): Wv.
__global__ __launch_bounds__(256) void prep_kernel(const float* __restrict__ x,
                                                   const float* __restrict__ Wq,
                                                   const float* __restrict__ Wk,
                                                   const float* __restrict__ Wv,
                                                   u16* __restrict__ xb, u16* __restrict__ wt) {
  __shared__ float tile[64][65];
  int bid = blockIdx.x;
  if (bid < 1024) {
    int i = (bid * 256 + threadIdx.x) * 8;
    float4 a = *(const float4*)(x + i);
    float4 b = *(const float4*)(x + i + 4);
    s16x8 o;
    o[0] = (short)f2bf(a.x); o[1] = (short)f2bf(a.y);
    o[2] = (short)f2bf(a.z); o[3] = (short)f2bf(a.w);
    o[4] = (short)f2bf(b.x); o[5] = (short)f2bf(b.y);
    o[6] = (short)f2bf(b.z); o[7] = (short)f2bf(b.w);
    *(s16x8*)(xb + i) = o;
    return;
  }
  int t = bid - 1024;
  const float* src; int C, rowoff, j0, k0;
  if (t < 256) {                       // Wq / Wk: 16 j-tiles x 8 k-tiles each
    src = (t < 128) ? Wq : Wk;
    C = 1024; rowoff = (t < 128) ? 0 : 1024;
    int tt = t & 127;
    j0 = (tt & 15) * 64; k0 = (tt >> 4) * 64;
  } else {                             // Wv: 8 x 8
    src = Wv; C = 512; rowoff = 2048;
    int tt = t - 256;
    j0 = (tt & 7) * 64; k0 = (tt >> 3) * 64;
  }
  int tx = threadIdx.x % 64, ty4 = threadIdx.x / 64;
#pragma unroll
  for (int p = 0; p < 16; ++p) {
    int r = p * 4 + ty4;
    tile[r][tx] = src[(size_t)(k0 + r) * C + j0 + tx];
  }
  __syncthreads();
#pragma unroll
  for (int p = 0; p < 16; ++p) {
    int r = p * 4 + ty4;
    wt[(size_t)(rowoff + j0 + r) * 512 + k0 + tx] = f2bf(tile[tx][r]);
  }
}

// ---------------------------------------------------------------- fused QKV projection GEMM
// m97 recipe: single-buffer 32 KB LDS, 2 barriers/iter, DMA staging. (256,3) -> 3 WG/CU
// co-resident (all 640 WGs resident, no tail); wave-level overlap hides the barrier drain.
__global__ __launch_bounds__(256, 3) void gemm_qkv(const u16* __restrict__ xb, const u16* __restrict__ wt,
                                                   const float* __restrict__ bq, const float* __restrict__ bk,
                                                   const float* __restrict__ bv,
                                                   u16* __restrict__ qa, u16* __restrict__ ka,
                                                   u16* __restrict__ va) {
  __shared__ __align__(16) u16 As[128 * 64];
  __shared__ __align__(16) u16 Bs[128 * 64];
  int m0 = blockIdx.x * 128, j0 = blockIdx.y * 128;
  int tid = threadIdx.x;
  int w = tid >> 6, lane = tid & 63, quad = lane >> 4, l16 = lane & 15;
  int wr = (w >> 1) * 64, wc = (w & 1) * 64;

  // staging: slot s = it*256+tid; row = s>>3, logical chunk = (s&7)^(row&7), lds base wave-uniform
  int srow[4], scol[4], sbase[4];
#pragma unroll
  for (int it = 0; it < 4; ++it) {
    int s = it * 256 + tid;
    srow[it] = s >> 3;
    scol[it] = (s & 7) ^ ((s >> 3) & 7);
    sbase[it] = (s & ~63) * 8;
  }

  f32x4 acc[4][4];
#pragma unroll
  for (int i = 0; i < 4; ++i)
#pragma unroll
    for (int j = 0; j < 4; ++j)
#pragma unroll
      for (int r = 0; r < 4; ++r) acc[i][j][r] = 0.f;

  for (int kk = 0; kk < 8; ++kk) {
    int k0 = kk * 64;
    __syncthreads();                 // prev iteration's LDS reads done
#pragma unroll
    for (int it = 0; it < 4; ++it) {
      g2lds16(xb + (size_t)(m0 + srow[it]) * 512 + k0 + scol[it] * 8, &As[sbase[it]]);
      g2lds16(wt + (size_t)(j0 + srow[it]) * 512 + k0 + scol[it] * 8, &Bs[sbase[it]]);
    }
    __syncthreads();                 // barrier drain completes the DMA
#pragma unroll
    for (int kb = 0; kb < 2; ++kb) {
      s16x8 af[4], bfr[4];
#pragma unroll
      for (int rb = 0; rb < 4; ++rb) {
        int row = wr + rb * 16 + l16;
        af[rb] = *(const s16x8*)(&As[row * 64 + (((kb * 4 + quad) ^ (row & 7)) * 8)]);
      }
#pragma unroll
      for (int cb = 0; cb < 4; ++cb) {
        int row = wc + cb * 16 + l16;
        bfr[cb] = *(const s16x8*)(&Bs[row * 64 + (((kb * 4 + quad) ^ (row & 7)) * 8)]);
      }
#pragma unroll
      for (int rb = 0; rb < 4; ++rb)
#pragma unroll
        for (int cb = 0; cb < 4; ++cb)
          acc[rb][cb] = __builtin_amdgcn_mfma_f32_16x16x32_bf16(af[rb], bfr[cb], acc[rb][cb], 0, 0, 0);
    }
  }

#pragma unroll
  for (int cb = 0; cb < 4; ++cb) {
    int j = j0 + wc + cb * 16 + l16;
    float bias = (j < 1024) ? bq[j] : (j < 2048) ? bk[j - 1024] : bv[j - 2048];
#pragma unroll
    for (int rb = 0; rb < 4; ++rb) {
#pragma unroll
      for (int r = 0; r < 4; ++r) {
        int m = m0 + wr + rb * 16 + quad * 4 + r;
        int bidx = m >> 10, n = m & 1023;
        u16 o = f2bf(acc[rb][cb][r] + bias);
        if (j < 1024) {
          int h = j >> 7, r2 = j & 127;
          qa[((size_t)((bidx * 8 + h) * 1024 + n)) * 128 + r2] = o;
        } else if (j < 2048) {
          int jj = j - 1024, h = jj >> 7, r2 = jj & 127;
          ka[((size_t)((bidx * 8 + h) * 1024 + n)) * 128 + r2] = o;
        } else {                              // v transposed: [b][h][d][n]
          int jj = j - 2048, h = jj >> 6, d = jj & 63;
          va[((size_t)((bidx * 8 + h) * 64 + d)) * 1024 + n] = o;
        }
      }
    }
  }
}

// ---------------------------------------------------------------- differential attention v4 (unchanged from R4)
__global__ __launch_bounds__(256, 2) void attn_kernel(const u16* __restrict__ qa, const u16* __restrict__ ka,
                                                      const u16* __restrict__ va, float* __restrict__ out) {
  __shared__ __align__(16) u16 smem[17408];   // 34816 B
  u16* Ks = smem;                 // [kh][32 keys][16 chunks], content swizzled ^(row&7)  (16 KB)
  u16* Vs = smem + 8192;          // [kh][64 d][4 chunks], content swizzled ^(row&3)      (8 KB)
  u16* Ps = smem + 12288;         // [wave][hh][16 rows][40 cols]                         (10 KB)
  float* Ex = (float*)smem;       // epilogue overlay: [wi][hh][16][68] f32 over Ks+Vs

  int bh = blockIdx.x, b = bh >> 3, h = bh & 7;
  int q0 = blockIdx.y * 32;
  int tid = threadIdx.x, w = tid >> 6, lane = tid & 63, quad = lane >> 4, l16 = lane & 15;
  int kh = w >> 1;                // key-half this wave reduces over
  int qr = q0 + (w & 1) * 16;

  const u16* kgbase = ka + (size_t)bh * 1024 * 128;
  const u16* vgbase = va + (size_t)bh * 64 * 1024;

  const u16* qrow = qa + (size_t)(bh * 1024 + qr + l16) * 128;
  s16x8 qf[2][2];
  qf[0][0] = *(const s16x8*)(qrow + quad * 8);
  qf[0][1] = *(const s16x8*)(qrow + 32 + quad * 8);
  qf[1][0] = *(const s16x8*)(qrow + 64 + quad * 8);
  qf[1][1] = *(const s16x8*)(qrow + 96 + quad * 8);

  f32x4 O1[5], O2[5];
#pragma unroll
  for (int i = 0; i < 5; ++i)
#pragma unroll
    for (int r = 0; r < 4; ++r) { O1[i][r] = 0.f; O2[i][r] = 0.f; }

  s16x8 onesf;   // B-frag of the ones column: 1.0 only on lanes with l16==0
#pragma unroll
  for (int i = 0; i < 8; ++i) onesf[i] = (l16 == 0) ? (short)0x3F80 : (short)0;

  size_t kgo[4]; int kbse[4];
#pragma unroll
  for (int i = 0; i < 4; ++i) {
    int s = i * 256 + tid;
    int skh = s >> 9, row = (s >> 4) & 31, c = s & 15;
    kgo[i] = (size_t)(skh * 512 + row) * 128 + ((c ^ (row & 7)) * 8);   // + kt*32*128
    kbse[i] = (s & ~63) * 8;
  }
  size_t vgo[2]; int vbse[2];
#pragma unroll
  for (int i = 0; i < 2; ++i) {
    int s = i * 256 + tid;
    int skh = s >> 8, row = (s >> 2) & 63, c = s & 3;
    vgo[i] = (size_t)row * 1024 + skh * 512 + ((c ^ (row & 3)) * 8);    // + kt*32
    vbse[i] = (s & ~63) * 8;
  }

  for (int kt = 0; kt < 16; ++kt) {
    __syncthreads();                         // previous tile's LDS reads complete
#pragma unroll
    for (int i = 0; i < 4; ++i)
      g2lds16(kgbase + kgo[i] + (size_t)kt * 4096, &Ks[kbse[i]]);
#pragma unroll
    for (int i = 0; i < 2; ++i)
      g2lds16(vgbase + vgo[i] + (size_t)kt * 32, &Vs[vbse[i]]);
    __syncthreads();                         // barrier drain completes DMA

    s16x8 vf[4];
#pragma unroll
    for (int ct = 0; ct < 4; ++ct) {
      int row = ct * 16 + l16;
      vf[ct] = *(const s16x8*)(&Vs[kh * 2048 + row * 32 + ((quad ^ (row & 3)) * 8)]);
    }

#pragma unroll
    for (int hh = 0; hh < 2; ++hh) {
#pragma unroll
      for (int nt = 0; nt < 2; ++nt) {
        f32x4 sv; sv[0] = sv[1] = sv[2] = sv[3] = 0.f;
#pragma unroll
        for (int kb = 0; kb < 2; ++kb) {
          int row = nt * 16 + l16;
          s16x8 kf = *(const s16x8*)(&Ks[kh * 4096 + row * 128 +
                                         (((hh * 8 + kb * 4 + quad) ^ (row & 7)) * 8)]);
          sv = __builtin_amdgcn_mfma_f32_16x16x32_bf16(qf[hh][kb], kf, sv, 0, 0, 0);
        }
#pragma unroll
        for (int r = 0; r < 4; ++r)
          Ps[((w * 2 + hh) * 16 + quad * 4 + r) * 40 + nt * 16 + l16] = f2bf(__expf(sv[r] * 0.125f));
      }
    }
    asm volatile("s_waitcnt lgkmcnt(0)" ::: "memory");  // P writes retired before re-read
    s16x8 pf0 = *(const s16x8*)(&Ps[((w * 2 + 0) * 16 + l16) * 40 + quad * 8]);
    s16x8 pf1 = *(const s16x8*)(&Ps[((w * 2 + 1) * 16 + l16) * 40 + quad * 8]);
#pragma unroll
    for (int ct = 0; ct < 5; ++ct) {
      s16x8 bfr = (ct < 4) ? vf[ct] : onesf;
      O1[ct] = __builtin_amdgcn_mfma_f32_16x16x32_bf16(pf0, bfr, O1[ct], 0, 0, 0);
      O2[ct] = __builtin_amdgcn_mfma_f32_16x16x32_bf16(pf1, bfr, O2[ct], 0, 0, 0);
    }
  }
  __syncthreads();   // all waves done with Ks/Vs before Ex overlay

  if (w >= 2) {
    int wi = w - 2;
#pragma unroll
    for (int ct = 0; ct < 4; ++ct)
#pragma unroll
      for (int r = 0; r < 4; ++r) {
        Ex[((wi * 2 + 0) * 16 + quad * 4 + r) * 68 + ct * 16 + l16] = O1[ct][r];
        Ex[((wi * 2 + 1) * 16 + quad * 4 + r) * 68 + ct * 16 + l16] = O2[ct][r];
      }
    if (l16 == 0) {
#pragma unroll
      for (int r = 0; r < 4; ++r) {
        Ex[((wi * 2 + 0) * 16 + quad * 4 + r) * 68 + 64] = O1[4][r];
        Ex[((wi * 2 + 1) * 16 + quad * 4 + r) * 68 + 64] = O2[4][r];
      }
    }
  }
  __syncthreads();
  if (w < 2) {
#pragma unroll
    for (int ct = 0; ct < 4; ++ct)
#pragma unroll
      for (int r = 0; r < 4; ++r) {
        O1[ct][r] += Ex[((w * 2 + 0) * 16 + quad * 4 + r) * 68 + ct * 16 + l16];
        O2[ct][r] += Ex[((w * 2 + 1) * 16 + quad * 4 + r) * 68 + ct * 16 + l16];
      }
    if (l16 == 0) {
#pragma unroll
      for (int r = 0; r < 4; ++r) {
        O1[4][r] += Ex[((w * 2 + 0) * 16 + quad * 4 + r) * 68 + 64];
        O2[4][r] += Ex[((w * 2 + 1) * 16 + quad * 4 + r) * 68 + 64];
      }
    }
    float inv1[4], inv2[4];
#pragma unroll
    for (int r = 0; r < 4; ++r) {
      float l1 = __shfl(O1[4][r], lane & 48, 64);
      float l2 = __shfl(O2[4][r], lane & 48, 64);
      inv1[r] = 1.0f / l1;
      inv2[r] = 1.0f / l2;
    }
    int nb = qr + quad * 4;
#pragma unroll
    for (int ct = 0; ct < 4; ++ct)
#pragma unroll
      for (int r = 0; r < 4; ++r) {
        float val = O1[ct][r] * inv1[r] - 0.5f * O2[ct][r] * inv2[r];
        out[(size_t)(b * 1024 + nb + r) * 512 + h * 64 + ct * 16 + l16] = val;
      }
  }
}

// ---------------------------------------------------------------- launcher
extern "C" void kernel_launch(void* const* d_in, const int* in_sizes, int n_in,
                              void* d_out, int out_size, void* d_ws, size_t ws_size,
                              hipStream_t stream) {
  (void)in_sizes; (void)n_in; (void)out_size; (void)ws_size;
  const float* x  = (const float*)d_in[0];
  const float* Wq = (const float*)d_in[1];
  const float* bq = (const float*)d_in[2];
  const float* Wk = (const float*)d_in[3];
  const float* bk = (const float*)d_in[4];
  const float* Wv = (const float*)d_in[5];
  const float* bv = (const float*)d_in[6];
  float* out = (float*)d_out;

  char* ws = (char*)d_ws;
  u16* xb = (u16*)(ws);                    // 4096*512*2   = 4 MiB
  u16* wt = (u16*)(ws + 4194304);          // 2560*512*2   = 2.5 MiB
  u16* qa = (u16*)(ws + 6815744);          // 4*8*1024*128*2 = 8 MiB
  u16* ka = (u16*)(ws + 15204352);         // 8 MiB
  u16* va = (u16*)(ws + 23592960);         // 4*8*64*1024*2 = 4 MiB

  prep_kernel<<<1344, 256, 0, stream>>>(x, Wq, Wk, Wv, xb, wt);
  gemm_qkv<<<dim3(32, 20), 256, 0, stream>>>(xb, wt, bq, bk, bv, qa, ka, va);
  attn_kernel<<<dim3(32, 32), 256, 0, stream>>>(qa, ka, va, out);
}

// Round 6
// 139.381 us; speedup vs baseline: 1.5881x; 1.0042x over previous
//
#include <hip/hip_runtime.h>
#include <hip/hip_bf16.h>

typedef unsigned short u16;
typedef unsigned int u32;
typedef short s16x8 __attribute__((ext_vector_type(8)));
typedef float f32x4 __attribute__((ext_vector_type(4)));

// fp32 -> bf16 round-to-nearest-even
__device__ inline u16 f2bf(float f) {
  union { float f; unsigned int u; } v; v.f = f;
  unsigned int r = v.u + 0x7fffu + ((v.u >> 16) & 1u);
  return (u16)(r >> 16);
}

// async 16B global -> LDS DMA (lane i of the wave lands at ldsbase + i*16)
__device__ __forceinline__ void g2lds16(const u16* g, u16* l) {
  __builtin_amdgcn_global_load_lds((const __attribute__((address_space(1))) void*)g,
                                   (__attribute__((address_space(3))) void*)l, 16, 0, 0);
}

// ---------------------------------------------------------------- prep: cast x + transpose-cast W (one launch)
__global__ __launch_bounds__(256) void prep_kernel(const float* __restrict__ x,
                                                   const float* __restrict__ Wq,
                                                   const float* __restrict__ Wk,
                                                   const float* __restrict__ Wv,
                                                   u16* __restrict__ xb, u16* __restrict__ wt) {
  __shared__ float tile[64][65];
  int bid = blockIdx.x;
  if (bid < 1024) {
    int i = (bid * 256 + threadIdx.x) * 8;
    float4 a = *(const float4*)(x + i);
    float4 b = *(const float4*)(x + i + 4);
    s16x8 o;
    o[0] = (short)f2bf(a.x); o[1] = (short)f2bf(a.y);
    o[2] = (short)f2bf(a.z); o[3] = (short)f2bf(a.w);
    o[4] = (short)f2bf(b.x); o[5] = (short)f2bf(b.y);
    o[6] = (short)f2bf(b.z); o[7] = (short)f2bf(b.w);
    *(s16x8*)(xb + i) = o;
    return;
  }
  int t = bid - 1024;
  const float* src; int C, rowoff, j0, k0;
  if (t < 256) {
    src = (t < 128) ? Wq : Wk;
    C = 1024; rowoff = (t < 128) ? 0 : 1024;
    int tt = t & 127;
    j0 = (tt & 15) * 64; k0 = (tt >> 4) * 64;
  } else {
    src = Wv; C = 512; rowoff = 2048;
    int tt = t - 256;
    j0 = (tt & 7) * 64; k0 = (tt >> 3) * 64;
  }
  int tx = threadIdx.x % 64, ty4 = threadIdx.x / 64;
#pragma unroll
  for (int p = 0; p < 16; ++p) {
    int r = p * 4 + ty4;
    tile[r][tx] = src[(size_t)(k0 + r) * C + j0 + tx];
  }
  __syncthreads();
#pragma unroll
  for (int p = 0; p < 16; ++p) {
    int r = p * 4 + ty4;
    wt[(size_t)(rowoff + j0 + r) * 512 + k0 + tx] = f2bf(tile[tx][r]);
  }
}

// ---------------------------------------------------------------- fused QKV projection GEMM (unchanged from R5)
__global__ __launch_bounds__(256, 3) void gemm_qkv(const u16* __restrict__ xb, const u16* __restrict__ wt,
                                                   const float* __restrict__ bq, const float* __restrict__ bk,
                                                   const float* __restrict__ bv,
                                                   u16* __restrict__ qa, u16* __restrict__ ka,
                                                   u16* __restrict__ va) {
  __shared__ __align__(16) u16 As[128 * 64];
  __shared__ __align__(16) u16 Bs[128 * 64];
  int m0 = blockIdx.x * 128, j0 = blockIdx.y * 128;
  int tid = threadIdx.x;
  int w = tid >> 6, lane = tid & 63, quad = lane >> 4, l16 = lane & 15;
  int wr = (w >> 1) * 64, wc = (w & 1) * 64;

  int srow[4], scol[4], sbase[4];
#pragma unroll
  for (int it = 0; it < 4; ++it) {
    int s = it * 256 + tid;
    srow[it] = s >> 3;
    scol[it] = (s & 7) ^ ((s >> 3) & 7);
    sbase[it] = (s & ~63) * 8;
  }

  f32x4 acc[4][4];
#pragma unroll
  for (int i = 0; i < 4; ++i)
#pragma unroll
    for (int j = 0; j < 4; ++j)
#pragma unroll
      for (int r = 0; r < 4; ++r) acc[i][j][r] = 0.f;

  for (int kk = 0; kk < 8; ++kk) {
    int k0 = kk * 64;
    __syncthreads();
#pragma unroll
    for (int it = 0; it < 4; ++it) {
      g2lds16(xb + (size_t)(m0 + srow[it]) * 512 + k0 + scol[it] * 8, &As[sbase[it]]);
      g2lds16(wt + (size_t)(j0 + srow[it]) * 512 + k0 + scol[it] * 8, &Bs[sbase[it]]);
    }
    __syncthreads();
#pragma unroll
    for (int kb = 0; kb < 2; ++kb) {
      s16x8 af[4], bfr[4];
#pragma unroll
      for (int rb = 0; rb < 4; ++rb) {
        int row = wr + rb * 16 + l16;
        af[rb] = *(const s16x8*)(&As[row * 64 + (((kb * 4 + quad) ^ (row & 7)) * 8)]);
      }
#pragma unroll
      for (int cb = 0; cb < 4; ++cb) {
        int row = wc + cb * 16 + l16;
        bfr[cb] = *(const s16x8*)(&Bs[row * 64 + (((kb * 4 + quad) ^ (row & 7)) * 8)]);
      }
#pragma unroll
      for (int rb = 0; rb < 4; ++rb)
#pragma unroll
        for (int cb = 0; cb < 4; ++cb)
          acc[rb][cb] = __builtin_amdgcn_mfma_f32_16x16x32_bf16(af[rb], bfr[cb], acc[rb][cb], 0, 0, 0);
    }
  }

#pragma unroll
  for (int cb = 0; cb < 4; ++cb) {
    int j = j0 + wc + cb * 16 + l16;
    float bias = (j < 1024) ? bq[j] : (j < 2048) ? bk[j - 1024] : bv[j - 2048];
#pragma unroll
    for (int rb = 0; rb < 4; ++rb) {
#pragma unroll
      for (int r = 0; r < 4; ++r) {
        int m = m0 + wr + rb * 16 + quad * 4 + r;
        int bidx = m >> 10, n = m & 1023;
        u16 o = f2bf(acc[rb][cb][r] + bias);
        if (j < 1024) {
          int h = j >> 7, r2 = j & 127;
          qa[((size_t)((bidx * 8 + h) * 1024 + n)) * 128 + r2] = o;
        } else if (j < 2048) {
          int jj = j - 1024, h = jj >> 7, r2 = jj & 127;
          ka[((size_t)((bidx * 8 + h) * 1024 + n)) * 128 + r2] = o;
        } else {                              // v transposed: [b][h][d][n]
          int jj = j - 2048, h = jj >> 6, d = jj & 63;
          va[((size_t)((bidx * 8 + h) * 64 + d)) * 1024 + n] = o;
        }
      }
    }
  }
}

// ---------------------------------------------------------------- differential attention v5
// Transposed-score formulation: S^T = mfma(K,Q) (A/B frag layouts identical for 16x16x32, so the
// same register content works); P^T moves C-layout -> B-frag via 8 shfl + 4 selects (no LDS
// round-trip, no lgkm drain, no Ps buffer); O^T = mfma(V^T, P^T). Denominators accumulated in
// VALU from the same truncated-bf16 P values (ratio stays consistent); ones-column MFMAs gone.
__global__ __launch_bounds__(256, 2) void attn_kernel(const u16* __restrict__ qa, const u16* __restrict__ ka,
                                                      const u16* __restrict__ va, float* __restrict__ out) {
  __shared__ __align__(16) u16 smem[12288];   // 24 KB: Ks 16 KB + Vs 8 KB
  u16* Ks = smem;                 // [kh][32 keys][16 chunks], content swizzled ^(row&7)
  u16* Vs = smem + 8192;          // [kh][64 d][4 chunks], content swizzled ^(row&3)
  float* Ex = (float*)smem;       // epilogue overlay: [wi][64 lanes][35] f32 (17.9 KB)

  int bh = blockIdx.x, b = bh >> 3, h = bh & 7;
  int q0 = blockIdx.y * 32;
  int tid = threadIdx.x, w = tid >> 6, lane = tid & 63, quad = lane >> 4, l16 = lane & 15;
  int kh = w >> 1;                // key-half (sequence half) this wave reduces over
  int qr = q0 + (w & 1) * 16;

  const u16* kgbase = ka + (size_t)bh * 1024 * 128;
  const u16* vgbase = va + (size_t)bh * 64 * 1024;

  // q fragments: B-operand [k=feat][n=q-row]: l16 = q-row, quad*8+j = feat (same content as before)
  const u16* qrow = qa + (size_t)(bh * 1024 + qr + l16) * 128;
  s16x8 qf[2][2];
  qf[0][0] = *(const s16x8*)(qrow + quad * 8);
  qf[0][1] = *(const s16x8*)(qrow + 32 + quad * 8);
  qf[1][0] = *(const s16x8*)(qrow + 64 + quad * 8);
  qf[1][1] = *(const s16x8*)(qrow + 96 + quad * 8);

  f32x4 O1[4], O2[4];            // O^T: row = d (quad*4+r), col = q-row (l16)
#pragma unroll
  for (int i = 0; i < 4; ++i)
#pragma unroll
    for (int r = 0; r < 4; ++r) { O1[i][r] = 0.f; O2[i][r] = 0.f; }
  float lacc[2] = {0.f, 0.f};    // softmax denominators (partial: this lane's keys)

  size_t kgo[4]; int kbse[4];
#pragma unroll
  for (int i = 0; i < 4; ++i) {
    int s = i * 256 + tid;
    int skh = s >> 9, row = (s >> 4) & 31, c = s & 15;
    kgo[i] = (size_t)(skh * 512 + row) * 128 + ((c ^ (row & 7)) * 8);   // + kt*32*128
    kbse[i] = (s & ~63) * 8;
  }
  size_t vgo[2]; int vbse[2];
#pragma unroll
  for (int i = 0; i < 2; ++i) {
    int s = i * 256 + tid;
    int skh = s >> 8, row = (s >> 2) & 63, c = s & 3;
    vgo[i] = (size_t)row * 1024 + skh * 512 + ((c ^ (row & 3)) * 8);    // + kt*32
    vbse[i] = (s & ~63) * 8;
  }

  int srcLo = (quad & 1) * 32 + l16;    // C-quad (2*quad)&3
  int srcHi = srcLo + 16;               // C-quad (2*quad+1)&3
  bool hiSel = quad >= 2;               // keys 16..31 come from the nt=1 score tile

  for (int kt = 0; kt < 16; ++kt) {
    __syncthreads();                         // previous tile's LDS reads complete
#pragma unroll
    for (int i = 0; i < 4; ++i)
      g2lds16(kgbase + kgo[i] + (size_t)kt * 4096, &Ks[kbse[i]]);
#pragma unroll
    for (int i = 0; i < 2; ++i)
      g2lds16(vgbase + vgo[i] + (size_t)kt * 32, &Vs[vbse[i]]);
    __syncthreads();                         // barrier drain completes DMA

    // V^T fragments: A[m=d][k=key]: l16 = d, quad*8+j = key (same b128 loads as before)
    s16x8 vf[4];
#pragma unroll
    for (int ct = 0; ct < 4; ++ct) {
      int row = ct * 16 + l16;
      vf[ct] = *(const s16x8*)(&Vs[kh * 2048 + row * 32 + ((quad ^ (row & 3)) * 8)]);
    }

#pragma unroll
    for (int hh = 0; hh < 2; ++hh) {
      // S^T = K·Q^T: two key sub-tiles, C-layout key = quad*4+r, q = l16
      u32 pk[2][2];
#pragma unroll
      for (int nt = 0; nt < 2; ++nt) {
        f32x4 sv; sv[0] = sv[1] = sv[2] = sv[3] = 0.f;
#pragma unroll
        for (int kb = 0; kb < 2; ++kb) {
          int row = nt * 16 + l16;
          s16x8 kf = *(const s16x8*)(&Ks[kh * 4096 + row * 128 +
                                         (((hh * 8 + kb * 4 + quad) ^ (row & 7)) * 8)]);
          sv = __builtin_amdgcn_mfma_f32_16x16x32_bf16(kf, qf[hh][kb], sv, 0, 0, 0);
        }
        u32 ue[4];
#pragma unroll
        for (int r = 0; r < 4; ++r) {
          float e = __expf(sv[r] * 0.125f);
          ue[r] = __float_as_uint(e);
          lacc[hh] += __uint_as_float(ue[r] & 0xffff0000u);  // sum of truncated values
        }
        pk[nt][0] = (ue[0] >> 16) | (ue[1] & 0xffff0000u);   // keys (4q, 4q+1)
        pk[nt][1] = (ue[2] >> 16) | (ue[3] & 0xffff0000u);   // keys (4q+2, 4q+3)
      }
      // P^T B-frag: lane(quad,l16) needs keys 8*quad..+7 for q-col l16
      u32 a0 = __shfl(pk[0][0], srcLo), b0 = __shfl(pk[1][0], srcLo);
      u32 a1 = __shfl(pk[0][1], srcLo), b1 = __shfl(pk[1][1], srcLo);
      u32 a2 = __shfl(pk[0][0], srcHi), b2 = __shfl(pk[1][0], srcHi);
      u32 a3 = __shfl(pk[0][1], srcHi), b3 = __shfl(pk[1][1], srcHi);
      union { u32 wv[4]; s16x8 frag; } pu;
      pu.wv[0] = hiSel ? b0 : a0;
      pu.wv[1] = hiSel ? b1 : a1;
      pu.wv[2] = hiSel ? b2 : a2;
      pu.wv[3] = hiSel ? b3 : a3;
      // O^T += V^T · P^T
      if (hh == 0) {
#pragma unroll
        for (int ct = 0; ct < 4; ++ct)
          O1[ct] = __builtin_amdgcn_mfma_f32_16x16x32_bf16(vf[ct], pu.frag, O1[ct], 0, 0, 0);
      } else {
#pragma unroll
        for (int ct = 0; ct < 4; ++ct)
          O2[ct] = __builtin_amdgcn_mfma_f32_16x16x32_bf16(vf[ct], pu.frag, O2[ct], 0, 0, 0);
      }
    }
  }
  __syncthreads();   // all waves done with Ks/Vs before Ex overlay

  // ---- combine key-halves through LDS (waves 2,3 -> waves 0,1); stride 35 = conflict-free ----
  if (w >= 2) {
    int base = ((w - 2) * 64 + lane) * 35;
#pragma unroll
    for (int ct = 0; ct < 4; ++ct)
#pragma unroll
      for (int r = 0; r < 4; ++r) {
        Ex[base + ct * 4 + r] = O1[ct][r];
        Ex[base + 16 + ct * 4 + r] = O2[ct][r];
      }
    Ex[base + 32] = lacc[0];
    Ex[base + 33] = lacc[1];
  }
  __syncthreads();
  if (w < 2) {
    int base = (w * 64 + lane) * 35;
#pragma unroll
    for (int ct = 0; ct < 4; ++ct)
#pragma unroll
      for (int r = 0; r < 4; ++r) {
        O1[ct][r] += Ex[base + ct * 4 + r];
        O2[ct][r] += Ex[base + 16 + ct * 4 + r];
      }
    float l1 = lacc[0] + Ex[base + 32];
    float l2 = lacc[1] + Ex[base + 33];
    // reduce across the 4 quads (all hold the same q-col l16)
    l1 += __shfl_xor(l1, 16); l1 += __shfl_xor(l1, 32);
    l2 += __shfl_xor(l2, 16); l2 += __shfl_xor(l2, 32);
    float inv1 = 1.0f / l1, inv2 = 1.0f / l2;
    // lane holds q-row qr+l16, d = ct*16 + quad*4 + r  -> float4 stores
    float* orow = out + (size_t)(b * 1024 + qr + l16) * 512 + h * 64;
#pragma unroll
    for (int ct = 0; ct < 4; ++ct) {
      float4 v;
      v.x = O1[ct][0] * inv1 - 0.5f * O2[ct][0] * inv2;
      v.y = O1[ct][1] * inv1 - 0.5f * O2[ct][1] * inv2;
      v.z = O1[ct][2] * inv1 - 0.5f * O2[ct][2] * inv2;
      v.w = O1[ct][3] * inv1 - 0.5f * O2[ct][3] * inv2;
      *(float4*)(orow + ct * 16 + quad * 4) = v;
    }
  }
}

// ---------------------------------------------------------------- launcher
extern "C" void kernel_launch(void* const* d_in, const int* in_sizes, int n_in,
                              void* d_out, int out_size, void* d_ws, size_t ws_size,
                              hipStream_t stream) {
  (void)in_sizes; (void)n_in; (void)out_size; (void)ws_size;
  const float* x  = (const float*)d_in[0];
  const float* Wq = (const float*)d_in[1];
  const float* bq = (const float*)d_in[2];
  const float* Wk = (const float*)d_in[3];
  const float* bk = (const float*)d_in[4];
  const float* Wv = (const float*)d_in[5];
  const float* bv = (const float*)d_in[6];
  float* out = (float*)d_out;

  char* ws = (char*)d_ws;
  u16* xb = (u16*)(ws);                    // 4096*512*2   = 4 MiB
  u16* wt = (u16*)(ws + 4194304);          // 2560*512*2   = 2.5 MiB
  u16* qa = (u16*)(ws + 6815744);          // 4*8*1024*128*2 = 8 MiB
  u16* ka = (u16*)(ws + 15204352);         // 8 MiB
  u16* va = (u16*)(ws + 23592960);         // 4*8*64*1024*2 = 4 MiB

  prep_kernel<<<1344, 256, 0, stream>>>(x, Wq, Wk, Wv, xb, wt);
  gemm_qkv<<<dim3(32, 20), 256, 0, stream>>>(xb, wt, bq, bk, bv, qa, ka, va);
  attn_kernel<<<dim3(32, 32), 256, 0, stream>>>(qa, ka, va, out);
}